// Round 8
// baseline (374.115 us; speedup 1.0000x reference)
//
#include <hip/hip_runtime.h>

typedef __bf16 bf16_t;
typedef __bf16 bf16x8 __attribute__((ext_vector_type(8)));
typedef __bf16 bf16x4 __attribute__((ext_vector_type(4)));
typedef __bf16 bf16x2 __attribute__((ext_vector_type(2)));
typedef float f32x4 __attribute__((ext_vector_type(4)));
typedef float f32x16 __attribute__((ext_vector_type(16)));

#define B_ 2
#define S_ 2048
#define D_ 1024
#define H_ 16
#define HD_ 64

#define MFMA(a, b, c) __builtin_amdgcn_mfma_f32_16x16x32_bf16(a, b, c, 0, 0, 0)
#define MFMA32(a, b, c) __builtin_amdgcn_mfma_f32_32x32x16_bf16(a, b, c, 0, 0, 0)

static __device__ __forceinline__ bf16x8 ldb8(const bf16_t* p) {
    return *(const bf16x8*)p;
}

static __device__ __forceinline__ void gload16(const void* g, void* l) {
    __builtin_amdgcn_global_load_lds((const __attribute__((address_space(1))) void*)g,
                                     (__attribute__((address_space(3))) void*)l, 16, 0, 0);
}

// pack two f32 -> one u32 of 2 bf16 (lo=a, hi=b). Plain casts: compiler emits
// v_cvt_pk_bf16_f32 itself; no opaque asm (hazards modeled).
static __device__ __forceinline__ unsigned cvtpk(float a, float b) {
    union { bf16x2 h; unsigned u; } cv;
    cv.h[0] = (bf16_t)a;
    cv.h[1] = (bf16_t)b;
    return cv.u;
}
static __device__ __forceinline__ float xhalf_max(float x) {
    return fmaxf(x, __shfl_xor(x, 32));
}

// ---------------- fp32 -> bf16 convert ----------------
__global__ __launch_bounds__(256) void k_cvt(const float* __restrict__ in,
                                             bf16_t* __restrict__ out, int n4) {
    int i = blockIdx.x * 256 + threadIdx.x;
    int stride = gridDim.x * 256;
    for (; i < n4; i += stride) {
        float4 v = ((const float4*)in)[i];
        bf16x4 o;
        o[0] = (bf16_t)v.x; o[1] = (bf16_t)v.y; o[2] = (bf16_t)v.z; o[3] = (bf16_t)v.w;
        ((bf16x4*)out)[i] = o;
    }
}

// ---------------- shared GEMM main loop (C = A * Bt^T), 128x128 tile, BK=32 ----
static __device__ __forceinline__ void gemm_core(const bf16_t* __restrict__ A,
                                                 const bf16_t* __restrict__ Bt,
                                                 const int K, bf16_t* ldsA, bf16_t* ldsB,
                                                 f32x4 acc[4][4]) {
    const int tid = threadIdx.x;
    const int wave = tid >> 6, lane = tid & 63;
    const int g = lane >> 4, q16 = lane & 15;
    const int wm = wave >> 1, wn = wave & 1;
    const int mb = blockIdx.x * 128, nb = blockIdx.y * 128;
    const int r0 = lane >> 2, c8 = (lane & 3) * 8;

#pragma unroll
    for (int i = 0; i < 4; ++i)
#pragma unroll
        for (int j = 0; j < 4; ++j) {
            f32x4 z = {0.f, 0.f, 0.f, 0.f};
            acc[i][j] = z;
        }

    const bf16_t* ga0 = A + (size_t)(mb + wave * 16 + r0) * K + c8;
    const bf16_t* ga1 = A + (size_t)(mb + 64 + wave * 16 + r0) * K + c8;
    const bf16_t* gb0 = Bt + (size_t)(nb + wave * 16 + r0) * K + c8;
    const bf16_t* gb1 = Bt + (size_t)(nb + 64 + wave * 16 + r0) * K + c8;
    bf16_t* la0 = ldsA + (wave * 16) * 32;
    bf16_t* la1 = ldsA + (64 + wave * 16) * 32;
    bf16_t* lb0 = ldsB + (wave * 16) * 32;
    bf16_t* lb1 = ldsB + (64 + wave * 16) * 32;

    for (int k0 = 0; k0 < K; k0 += 32) {
        gload16(ga0 + k0, la0);
        gload16(ga1 + k0, la1);
        gload16(gb0 + k0, lb0);
        gload16(gb1 + k0, lb1);
        __syncthreads();
        bf16x8 af[4], bfv[4];
#pragma unroll
        for (int i = 0; i < 4; ++i)
            af[i] = ldb8(ldsA + (wm * 64 + i * 16 + q16) * 32 + 8 * g);
#pragma unroll
        for (int j = 0; j < 4; ++j)
            bfv[j] = ldb8(ldsB + (wn * 64 + j * 16 + q16) * 32 + 8 * g);
#pragma unroll
        for (int i = 0; i < 4; ++i)
#pragma unroll
            for (int j = 0; j < 4; ++j)
                acc[i][j] = MFMA(af[i], bfv[j], acc[i][j]);
        __syncthreads();
    }
}

// ---------------- GEMM1: qkv = x @ w_qkv^T + b, fused RoPE, scatter to q/k/vT ----
__global__ __launch_bounds__(256) void k_gemm_qkv(const bf16_t* __restrict__ xb,
                                                  const bf16_t* __restrict__ wqb,
                                                  const float* __restrict__ bqkv,
                                                  const float* __restrict__ rot,
                                                  bf16_t* __restrict__ qa,
                                                  bf16_t* __restrict__ ka,
                                                  bf16_t* __restrict__ vT) {
    __shared__ bf16_t ldsA[128 * 32];
    __shared__ bf16_t ldsB[128 * 32];
    f32x4 acc[4][4];
    gemm_core(xb, wqb, 1024, ldsA, ldsB, acc);

    const int tid = threadIdx.x;
    const int wave = tid >> 6, lane = tid & 63;
    const int g = lane >> 4, q16 = lane & 15;
    const int wm = wave >> 1, wn = wave & 1;
    const int mb = blockIdx.x * 128, nb = blockIdx.y * 128;
    const int third = nb >> 10;  // 0=q, 1=k, 2=v
    const float QS = 0.125f * 1.44269504088896f;  // softmax scale * log2(e)

    if (third < 2) {
        bf16_t* dst = (third == 0) ? qa : ka;
        const float2* cs2 = (const float2*)rot;
#pragma unroll
        for (int j = 0; j < 4; ++j) {
            int n = nb + wn * 64 + j * 16 + q16;
            float bias = bqkv[n];
            int d = n & 1023;
            int h = d >> 6, hd = d & 63;
            int i2 = hd >> 1;
            bool odd = (hd & 1) != 0;
#pragma unroll
            for (int i = 0; i < 4; ++i) {
                int m0 = mb + wm * 64 + i * 16 + 4 * g;
#pragma unroll
                for (int r = 0; r < 4; ++r) {
                    int mm = m0 + r;
                    int s = mm & 2047, b = mm >> 11;
                    float val = acc[i][j][r] + bias;
                    float prt = __shfl_xor(val, 1);
                    float2 cs = cs2[s * 32 + i2];
                    float rv = val * cs.x + (odd ? prt * cs.y : -(prt * cs.y));
                    if (third == 0) rv *= QS;
                    dst[((size_t)(b * H_ + h) * S_ + s) * HD_ + hd] = (bf16_t)rv;
                }
            }
        }
    } else {
#pragma unroll
        for (int j = 0; j < 4; ++j) {
            int n = nb + wn * 64 + j * 16 + q16;
            float bias = bqkv[n];
            int d = n & 1023;
            int h = d >> 6, hd = d & 63;
#pragma unroll
            for (int i = 0; i < 4; ++i) {
                int m0 = mb + wm * 64 + i * 16 + 4 * g;
                int s0 = m0 & 2047, b = m0 >> 11;
                bf16x4 pk;
#pragma unroll
                for (int r = 0; r < 4; ++r) pk[r] = (bf16_t)(acc[i][j][r] + bias);
                *(bf16x4*)(vT + ((size_t)(b * H_ + h) * HD_ + hd) * S_ + s0) = pk;
            }
        }
    }
}

// ---------------- flash attention ----------------
// t-split: 4 waves/block; waves (p, p+2) share 32 q-rows (p=wave&1), cover
// t-halves [0,1024) / [1024,2048); exact online-softmax merge via LDS.
// Per tile of 32 t: swapped QK^T (mfma(K,Q)) -> lane holds S'[t][q=lane&31];
// softmax fully in-register; P->A-frag via cvt_pk + __shfl_xor(32)+hi-select;
// l via ones-MFMA (lands in O layout). Score pipeline: QK of tile i+1 issued
// adjacent to softmax of tile i (MFMA||VALU overlap), setprio(1) on MFMA.
#define NTT 32  // tiles of 32 t per wave (1024 t)

static __device__ __forceinline__ void load_kv(const bf16_t* kbase, const bf16_t* vbase,
                                               bf16x8 (&kf)[4], bf16x8 (&vf)[4]) {
#pragma unroll
    for (int j = 0; j < 4; ++j) kf[j] = ldb8(kbase + 16 * j);
    vf[0] = ldb8(vbase);
    vf[1] = ldb8(vbase + 32 * S_);
    vf[2] = ldb8(vbase + 16);
    vf[3] = ldb8(vbase + 16 + 32 * S_);
}

static __device__ __forceinline__ f32x16 qk4(const bf16x8 (&kf)[4], const bf16x8 (&qf)[4]) {
    f32x16 s = {0.f, 0.f, 0.f, 0.f, 0.f, 0.f, 0.f, 0.f,
                0.f, 0.f, 0.f, 0.f, 0.f, 0.f, 0.f, 0.f};
    __builtin_amdgcn_s_setprio(1);
#pragma unroll
    for (int j = 0; j < 4; ++j) s = MFMA32(kf[j], qf[j], s);
    __builtin_amdgcn_s_setprio(0);
    return s;
}

static __device__ __forceinline__ void softmax_pa(f32x16& s, float& m,
                                                  f32x16& o0, f32x16& o1, f32x16& lac,
                                                  int hi, bf16x8& pa0v, bf16x8& pa1v) {
    float a0 = fmaxf(fmaxf(s[0], s[1]), s[2]);
    float a1 = fmaxf(fmaxf(s[3], s[4]), s[5]);
    float a2 = fmaxf(fmaxf(s[6], s[7]), s[8]);
    float a3 = fmaxf(fmaxf(s[9], s[10]), s[11]);
    float a4 = fmaxf(fmaxf(s[12], s[13]), s[14]);
    float tm = fmaxf(fmaxf(fmaxf(a0, a1), a2), fmaxf(fmaxf(a3, a4), s[15]));
    tm = xhalf_max(tm);  // lane^32 shares the q-row

    bool ok = (tm <= m + 8.0f);  // defer-max threshold (exp2 domain)
    if (!__all(ok)) {
        float mn = fmaxf(m, tm);
        float ce = __builtin_amdgcn_exp2f(m - mn);
        m = mn;
#pragma unroll
        for (int r = 0; r < 16; ++r) {
            int q = (r & 3) + 8 * (r >> 2) + 4 * hi;
            float c = __shfl(ce, q);
            o0[r] *= c; o1[r] *= c; lac[r] *= c;
        }
    }

#pragma unroll
    for (int r = 0; r < 16; ++r) s[r] = __builtin_amdgcn_exp2f(s[r] - m);

    unsigned c0 = cvtpk(s[0], s[1]),   c1 = cvtpk(s[2], s[3]);
    unsigned c2 = cvtpk(s[4], s[5]),   c3 = cvtpk(s[6], s[7]);
    unsigned d0 = cvtpk(s[8], s[9]),   d1 = cvtpk(s[10], s[11]);
    unsigned d2 = cvtpk(s[12], s[13]), d3 = cvtpk(s[14], s[15]);
    unsigned x0 = __shfl_xor(c0, 32), x1 = __shfl_xor(c1, 32);
    unsigned x2 = __shfl_xor(c2, 32), x3 = __shfl_xor(c3, 32);
    unsigned y0 = __shfl_xor(d0, 32), y1 = __shfl_xor(d1, 32);
    unsigned y2 = __shfl_xor(d2, 32), y3 = __shfl_xor(d3, 32);

    union { unsigned u[4]; bf16x8 v; } pa0, pa1;
    pa0.u[0] = hi ? x2 : c0;
    pa0.u[1] = hi ? x3 : c1;
    pa0.u[2] = hi ? c2 : x0;
    pa0.u[3] = hi ? c3 : x1;
    pa1.u[0] = hi ? y2 : d0;
    pa1.u[1] = hi ? y3 : d1;
    pa1.u[2] = hi ? d2 : y0;
    pa1.u[3] = hi ? d3 : y1;
    pa0v = pa0.v;
    pa1v = pa1.v;
}

static __device__ __forceinline__ void pv6(const bf16x8 pa0, const bf16x8 pa1,
                                           const bf16x8 (&vf)[4], const bf16x8 ones,
                                           f32x16& o0, f32x16& o1, f32x16& lac) {
    __builtin_amdgcn_s_setprio(1);
    o0 = MFMA32(pa0, vf[0], o0);
    o1 = MFMA32(pa0, vf[1], o1);
    o0 = MFMA32(pa1, vf[2], o0);
    o1 = MFMA32(pa1, vf[3], o1);
    lac = MFMA32(pa0, ones, lac);
    lac = MFMA32(pa1, ones, lac);
    __builtin_amdgcn_s_setprio(0);
}

__global__ __launch_bounds__(256, 4) void k_attn(const bf16_t* __restrict__ qa,
                                                 const bf16_t* __restrict__ ka,
                                                 const bf16_t* __restrict__ vT,
                                                 bf16_t* __restrict__ attn) {
    __shared__ float lm[2][32];
    __shared__ float lo[2][3][16][64];  // [pair][o0/o1/lac][reg][lane]
    const int tid = threadIdx.x;
    const int wave = tid >> 6, lane = tid & 63;
    const int l31 = lane & 31, hi = lane >> 5;
    const int pair = wave & 1;    // q-group in block
    const int thalf = wave >> 1;  // t-half
    const int bh = blockIdx.y;
    const int q0 = blockIdx.x * 64 + pair * 32;

    const bf16_t* Qp = qa + ((size_t)bh * S_ + q0) * HD_;
    const bf16_t* Kp = ka + (size_t)bh * S_ * HD_ + (size_t)thalf * 1024 * HD_;
    const bf16_t* Vp = vT + (size_t)bh * HD_ * S_ + thalf * 1024;

    bf16x8 qf[4];
    const bf16_t* qptr = Qp + l31 * HD_ + 8 * hi;
#pragma unroll
    for (int j = 0; j < 4; ++j) qf[j] = ldb8(qptr + 16 * j);

    bf16x8 ones;
#pragma unroll
    for (int i = 0; i < 8; ++i) ones[i] = (bf16_t)1.0f;

    const bf16_t* kl = Kp + l31 * HD_ + 8 * hi;
    const bf16_t* vl = Vp + l31 * S_ + 8 * hi;

    f32x16 o0 = {0.f, 0.f, 0.f, 0.f, 0.f, 0.f, 0.f, 0.f,
                 0.f, 0.f, 0.f, 0.f, 0.f, 0.f, 0.f, 0.f};
    f32x16 o1 = o0, lac = o0;
    float m = -1e30f;

    bf16x8 kA[4], vA[4], kB[4], vB[4];
    load_kv(kl, vl, kA, vA);
    f32x16 s = qk4(kA, qf);
    load_kv(kl + 32 * HD_, vl + 32, kB, vB);
    kl += 64 * HD_;
    vl += 64;

    for (int i = 0; i < NTT - 2; i += 2) {
        // tile i (s, vA ready), tile i+1 scores from kB
        f32x16 s2 = qk4(kB, qf);
        bf16x8 pa0, pa1;
        softmax_pa(s, m, o0, o1, lac, hi, pa0, pa1);
        pv6(pa0, pa1, vA, ones, o0, o1, lac);
        load_kv(kl, vl, kA, vA);  // tile i+2
        // tile i+1
        bf16x8 pb0, pb1;
        softmax_pa(s2, m, o0, o1, lac, hi, pb0, pb1);
        pv6(pb0, pb1, vB, ones, o0, o1, lac);
        s = qk4(kA, qf);                             // tile i+2 scores
        load_kv(kl + 32 * HD_, vl + 32, kB, vB);     // tile i+3
        kl += 64 * HD_;
        vl += 64;
    }
    // tail: tiles NTT-2 (s, vA), NTT-1 (kB, vB)
    {
        f32x16 s2 = qk4(kB, qf);
        bf16x8 pa0, pa1;
        softmax_pa(s, m, o0, o1, lac, hi, pa0, pa1);
        pv6(pa0, pa1, vA, ones, o0, o1, lac);
        bf16x8 pb0, pb1;
        softmax_pa(s2, m, o0, o1, lac, hi, pb0, pb1);
        pv6(pb0, pb1, vB, ones, o0, o1, lac);
    }

    // ---- merge t-halves: waves (p, p+2) share q-rows ----
    if (thalf) {
        if (!hi) lm[pair][l31] = m;
#pragma unroll
        for (int r = 0; r < 16; ++r) {
            lo[pair][0][r][lane] = o0[r];
            lo[pair][1][r][lane] = o1[r];
            lo[pair][2][r][lane] = lac[r];
        }
    }
    __syncthreads();
    if (!thalf) {
        float mb = lm[pair][l31];
        float ms = fmaxf(m, mb);
        float ca = __builtin_amdgcn_exp2f(m - ms);
        float cb = __builtin_amdgcn_exp2f(mb - ms);
        const int b = bh >> 4, h = bh & 15;
        bf16_t* op = attn + ((size_t)b * S_ + q0) * D_ + h * HD_;
#pragma unroll
        for (int r = 0; r < 16; ++r) {
            int q = (r & 3) + 8 * (r >> 2) + 4 * hi;
            float caq = __shfl(ca, q);
            float cbq = __shfl(cb, q);
            float O0 = o0[r] * caq + lo[pair][0][r][lane] * cbq;
            float O1 = o1[r] * caq + lo[pair][1][r][lane] * cbq;
            float L  = lac[r] * caq + lo[pair][2][r][lane] * cbq;
            float inv = 1.0f / L;
            op[(size_t)q * D_ + l31] = (bf16_t)(O0 * inv);
            op[(size_t)q * D_ + 32 + l31] = (bf16_t)(O1 * inv);
        }
    }
}

// ---------------- GEMM2: out = attn @ w_o^T + b_o (fp32 out) ----------------
__global__ __launch_bounds__(256) void k_gemm_out(const bf16_t* __restrict__ attn,
                                                  const bf16_t* __restrict__ wob,
                                                  const float* __restrict__ bo,
                                                  float* __restrict__ out) {
    __shared__ bf16_t ldsA[128 * 32];
    __shared__ bf16_t ldsB[128 * 32];
    f32x4 acc[4][4];
    gemm_core(attn, wob, 1024, ldsA, ldsB, acc);

    const int tid = threadIdx.x;
    const int wave = tid >> 6, lane = tid & 63;
    const int g = lane >> 4, q16 = lane & 15;
    const int wm = wave >> 1, wn = wave & 1;
    const int mb = blockIdx.x * 128, nb = blockIdx.y * 128;
#pragma unroll
    for (int j = 0; j < 4; ++j) {
        int n = nb + wn * 64 + j * 16 + q16;
        float bias = bo[n];
#pragma unroll
        for (int i = 0; i < 4; ++i) {
            int m0 = mb + wm * 64 + i * 16 + 4 * g;
#pragma unroll
            for (int r = 0; r < 4; ++r)
                out[(size_t)(m0 + r) * D_ + n] = acc[i][j][r] + bias;
        }
    }
}

extern "C" void kernel_launch(void* const* d_in, const int* in_sizes, int n_in,
                              void* d_out, int out_size, void* d_ws, size_t ws_size,
                              hipStream_t stream) {
    const float* x    = (const float*)d_in[0];
    const float* rot  = (const float*)d_in[1];
    const float* wqkv = (const float*)d_in[2];
    const float* bqkv = (const float*)d_in[3];
    const float* wo   = (const float*)d_in[4];
    const float* bo   = (const float*)d_in[5];
    float* out = (float*)d_out;

    char* ws = (char*)d_ws;
    bf16_t* xb   = (bf16_t*)(ws);                        // 8 MB  [4096,1024]
    bf16_t* wqb  = (bf16_t*)(ws + ((size_t)8 << 20));    // 6 MB  [3072,1024]
    bf16_t* wob  = (bf16_t*)(ws + ((size_t)14 << 20));   // 2 MB  [1024,1024]
    bf16_t* qa   = (bf16_t*)(ws + ((size_t)16 << 20));   // 8 MB  [B,H,S,64]
    bf16_t* ka   = (bf16_t*)(ws + ((size_t)24 << 20));   // 8 MB  [B,H,S,64]
    bf16_t* vT   = (bf16_t*)(ws + ((size_t)32 << 20));   // 8 MB  [B,H,64,S]
    bf16_t* attn = (bf16_t*)(ws + ((size_t)40 << 20));   // 8 MB  [4096,1024]

    k_cvt<<<1024, 256, 0, stream>>>(x, xb, (B_ * S_ * D_) / 4);
    k_cvt<<<1024, 256, 0, stream>>>(wqkv, wqb, (3 * D_ * D_) / 4);
    k_cvt<<<1024, 256, 0, stream>>>(wo, wob, (D_ * D_) / 4);
    k_gemm_qkv<<<dim3(32, 24), 256, 0, stream>>>(xb, wqb, bqkv, rot, qa, ka, vT);
    k_attn<<<dim3(32, 32), 256, 0, stream>>>(qa, ka, vT, attn);
    k_gemm_out<<<dim3(32, 8), 256, 0, stream>>>(attn, wob, bo, out);
}

// Round 9
// 283.574 us; speedup vs baseline: 1.3193x; 1.3193x over previous
//
#include <hip/hip_runtime.h>

typedef __bf16 bf16_t;
typedef __bf16 bf16x8 __attribute__((ext_vector_type(8)));
typedef __bf16 bf16x4 __attribute__((ext_vector_type(4)));
typedef __bf16 bf16x2 __attribute__((ext_vector_type(2)));
typedef float f32x4 __attribute__((ext_vector_type(4)));
typedef float f32x16 __attribute__((ext_vector_type(16)));

#define B_ 2
#define S_ 2048
#define D_ 1024
#define H_ 16
#define HD_ 64

#define MFMA(a, b, c) __builtin_amdgcn_mfma_f32_16x16x32_bf16(a, b, c, 0, 0, 0)
#define MFMA32(a, b, c) __builtin_amdgcn_mfma_f32_32x32x16_bf16(a, b, c, 0, 0, 0)

static __device__ __forceinline__ bf16x8 ldb8(const bf16_t* p) {
    return *(const bf16x8*)p;
}

static __device__ __forceinline__ void gload16(const void* g, void* l) {
    __builtin_amdgcn_global_load_lds((const __attribute__((address_space(1))) void*)g,
                                     (__attribute__((address_space(3))) void*)l, 16, 0, 0);
}

// pack two f32 -> one u32 of 2 bf16 (lo=a, hi=b). Plain casts: compiler emits
// v_cvt_pk_bf16_f32 itself; no opaque asm (hazards modeled).
static __device__ __forceinline__ unsigned cvtpk(float a, float b) {
    union { bf16x2 h; unsigned u; } cv;
    cv.h[0] = (bf16_t)a;
    cv.h[1] = (bf16_t)b;
    return cv.u;
}
static __device__ __forceinline__ float xhalf_max(float x) {
    return fmaxf(x, __shfl_xor(x, 32));
}

// ---------------- fp32 -> bf16 convert ----------------
__global__ __launch_bounds__(256) void k_cvt(const float* __restrict__ in,
                                             bf16_t* __restrict__ out, int n4) {
    int i = blockIdx.x * 256 + threadIdx.x;
    int stride = gridDim.x * 256;
    for (; i < n4; i += stride) {
        float4 v = ((const float4*)in)[i];
        bf16x4 o;
        o[0] = (bf16_t)v.x; o[1] = (bf16_t)v.y; o[2] = (bf16_t)v.z; o[3] = (bf16_t)v.w;
        ((bf16x4*)out)[i] = o;
    }
}

// ---------------- shared GEMM main loop (C = A * Bt^T), 128x128 tile, BK=32 ----
static __device__ __forceinline__ void gemm_core(const bf16_t* __restrict__ A,
                                                 const bf16_t* __restrict__ Bt,
                                                 const int K, bf16_t* ldsA, bf16_t* ldsB,
                                                 f32x4 acc[4][4]) {
    const int tid = threadIdx.x;
    const int wave = tid >> 6, lane = tid & 63;
    const int g = lane >> 4, q16 = lane & 15;
    const int wm = wave >> 1, wn = wave & 1;
    const int mb = blockIdx.x * 128, nb = blockIdx.y * 128;
    const int r0 = lane >> 2, c8 = (lane & 3) * 8;

#pragma unroll
    for (int i = 0; i < 4; ++i)
#pragma unroll
        for (int j = 0; j < 4; ++j) {
            f32x4 z = {0.f, 0.f, 0.f, 0.f};
            acc[i][j] = z;
        }

    const bf16_t* ga0 = A + (size_t)(mb + wave * 16 + r0) * K + c8;
    const bf16_t* ga1 = A + (size_t)(mb + 64 + wave * 16 + r0) * K + c8;
    const bf16_t* gb0 = Bt + (size_t)(nb + wave * 16 + r0) * K + c8;
    const bf16_t* gb1 = Bt + (size_t)(nb + 64 + wave * 16 + r0) * K + c8;
    bf16_t* la0 = ldsA + (wave * 16) * 32;
    bf16_t* la1 = ldsA + (64 + wave * 16) * 32;
    bf16_t* lb0 = ldsB + (wave * 16) * 32;
    bf16_t* lb1 = ldsB + (64 + wave * 16) * 32;

    for (int k0 = 0; k0 < K; k0 += 32) {
        gload16(ga0 + k0, la0);
        gload16(ga1 + k0, la1);
        gload16(gb0 + k0, lb0);
        gload16(gb1 + k0, lb1);
        __syncthreads();
        bf16x8 af[4], bfv[4];
#pragma unroll
        for (int i = 0; i < 4; ++i)
            af[i] = ldb8(ldsA + (wm * 64 + i * 16 + q16) * 32 + 8 * g);
#pragma unroll
        for (int j = 0; j < 4; ++j)
            bfv[j] = ldb8(ldsB + (wn * 64 + j * 16 + q16) * 32 + 8 * g);
#pragma unroll
        for (int i = 0; i < 4; ++i)
#pragma unroll
            for (int j = 0; j < 4; ++j)
                acc[i][j] = MFMA(af[i], bfv[j], acc[i][j]);
        __syncthreads();
    }
}

// ---------------- GEMM1: qkv = x @ w_qkv^T + b, fused RoPE, scatter to q/k/vT ----
__global__ __launch_bounds__(256) void k_gemm_qkv(const bf16_t* __restrict__ xb,
                                                  const bf16_t* __restrict__ wqb,
                                                  const float* __restrict__ bqkv,
                                                  const float* __restrict__ rot,
                                                  bf16_t* __restrict__ qa,
                                                  bf16_t* __restrict__ ka,
                                                  bf16_t* __restrict__ vT) {
    __shared__ bf16_t ldsA[128 * 32];
    __shared__ bf16_t ldsB[128 * 32];
    f32x4 acc[4][4];
    gemm_core(xb, wqb, 1024, ldsA, ldsB, acc);

    const int tid = threadIdx.x;
    const int wave = tid >> 6, lane = tid & 63;
    const int g = lane >> 4, q16 = lane & 15;
    const int wm = wave >> 1, wn = wave & 1;
    const int mb = blockIdx.x * 128, nb = blockIdx.y * 128;
    const int third = nb >> 10;  // 0=q, 1=k, 2=v
    const float QS = 0.125f * 1.44269504088896f;  // softmax scale * log2(e)

    if (third < 2) {
        bf16_t* dst = (third == 0) ? qa : ka;
        const float2* cs2 = (const float2*)rot;
#pragma unroll
        for (int j = 0; j < 4; ++j) {
            int n = nb + wn * 64 + j * 16 + q16;
            float bias = bqkv[n];
            int d = n & 1023;
            int h = d >> 6, hd = d & 63;
            int i2 = hd >> 1;
            bool odd = (hd & 1) != 0;
#pragma unroll
            for (int i = 0; i < 4; ++i) {
                int m0 = mb + wm * 64 + i * 16 + 4 * g;
#pragma unroll
                for (int r = 0; r < 4; ++r) {
                    int mm = m0 + r;
                    int s = mm & 2047, b = mm >> 11;
                    float val = acc[i][j][r] + bias;
                    float prt = __shfl_xor(val, 1);
                    float2 cs = cs2[s * 32 + i2];
                    float rv = val * cs.x + (odd ? prt * cs.y : -(prt * cs.y));
                    if (third == 0) rv *= QS;
                    dst[((size_t)(b * H_ + h) * S_ + s) * HD_ + hd] = (bf16_t)rv;
                }
            }
        }
    } else {
#pragma unroll
        for (int j = 0; j < 4; ++j) {
            int n = nb + wn * 64 + j * 16 + q16;
            float bias = bqkv[n];
            int d = n & 1023;
            int h = d >> 6, hd = d & 63;
#pragma unroll
            for (int i = 0; i < 4; ++i) {
                int m0 = mb + wm * 64 + i * 16 + 4 * g;
                int s0 = m0 & 2047, b = m0 >> 11;
                bf16x4 pk;
#pragma unroll
                for (int r = 0; r < 4; ++r) pk[r] = (bf16_t)(acc[i][j][r] + bias);
                *(bf16x4*)(vT + ((size_t)(b * H_ + h) * HD_ + hd) * S_ + s0) = pk;
            }
        }
    }
}

// ---------------- flash attention ----------------
// In-block t-split: 4 waves; waves (p, p+2) share 32 q-rows (p=wave&1), cover
// t-halves [0,1024)/[1024,2048); exact online-softmax merge via LDS epilogue.
// Per 32-t tile: swapped QK^T (mfma(K,Q)) -> lane holds S'[t][q=lane&31];
// in-register softmax; P->A-frags via cvt_pk + shfl_xor(32) + hi-select;
// row-sum kept as SCALAR lsum per lane (not ones-MFMA) to fit 128 regs at
// 4 waves/SIMD (round-8 lesson: >128 demand => 758MB scratch spill traffic).
static __device__ __forceinline__ void loadK(const bf16_t* kbase, bf16x8 (&kf)[4]) {
#pragma unroll
    for (int j = 0; j < 4; ++j) kf[j] = ldb8(kbase + 16 * j);
}
static __device__ __forceinline__ void loadV(const bf16_t* vbase, bf16x8 (&vf)[4]) {
    vf[0] = ldb8(vbase);
    vf[1] = ldb8(vbase + 32 * S_);
    vf[2] = ldb8(vbase + 16);
    vf[3] = ldb8(vbase + 16 + 32 * S_);
}

static __device__ __forceinline__ f32x16 qk4(const bf16x8 (&kf)[4], const bf16x8 (&qf)[4]) {
    f32x16 s = {0.f, 0.f, 0.f, 0.f, 0.f, 0.f, 0.f, 0.f,
                0.f, 0.f, 0.f, 0.f, 0.f, 0.f, 0.f, 0.f};
    __builtin_amdgcn_s_setprio(1);
#pragma unroll
    for (int j = 0; j < 4; ++j) s = MFMA32(kf[j], qf[j], s);
    __builtin_amdgcn_s_setprio(0);
    return s;
}

static __device__ __forceinline__ void softmax_pa(f32x16& s, float& m, float& lsum,
                                                  f32x16& o0, f32x16& o1,
                                                  int hi, bf16x8& pa0v, bf16x8& pa1v) {
    float a0 = fmaxf(fmaxf(s[0], s[1]), s[2]);
    float a1 = fmaxf(fmaxf(s[3], s[4]), s[5]);
    float a2 = fmaxf(fmaxf(s[6], s[7]), s[8]);
    float a3 = fmaxf(fmaxf(s[9], s[10]), s[11]);
    float a4 = fmaxf(fmaxf(s[12], s[13]), s[14]);
    float tm = fmaxf(fmaxf(fmaxf(a0, a1), a2), fmaxf(fmaxf(a3, a4), s[15]));
    tm = xhalf_max(tm);  // lane^32 shares the q-row

    bool ok = (tm <= m + 8.0f);  // defer-max threshold (exp2 domain)
    if (!__all(ok)) {
        float mn = fmaxf(m, tm);
        float ce = __builtin_amdgcn_exp2f(m - mn);
        m = mn;
        lsum *= ce;
#pragma unroll
        for (int r = 0; r < 16; ++r) {
            int q = (r & 3) + 8 * (r >> 2) + 4 * hi;
            float c = __shfl(ce, q);
            o0[r] *= c; o1[r] *= c;
        }
    }

#pragma unroll
    for (int r = 0; r < 16; ++r) s[r] = __builtin_amdgcn_exp2f(s[r] - m);
    float ps = (((s[0] + s[1]) + (s[2] + s[3])) + ((s[4] + s[5]) + (s[6] + s[7])))
             + (((s[8] + s[9]) + (s[10] + s[11])) + ((s[12] + s[13]) + (s[14] + s[15])));
    lsum += ps;

    unsigned c0 = cvtpk(s[0], s[1]),   c1 = cvtpk(s[2], s[3]);
    unsigned c2 = cvtpk(s[4], s[5]),   c3 = cvtpk(s[6], s[7]);
    unsigned d0 = cvtpk(s[8], s[9]),   d1 = cvtpk(s[10], s[11]);
    unsigned d2 = cvtpk(s[12], s[13]), d3 = cvtpk(s[14], s[15]);
    unsigned x0 = __shfl_xor(c0, 32), x1 = __shfl_xor(c1, 32);
    unsigned x2 = __shfl_xor(c2, 32), x3 = __shfl_xor(c3, 32);
    unsigned y0 = __shfl_xor(d0, 32), y1 = __shfl_xor(d1, 32);
    unsigned y2 = __shfl_xor(d2, 32), y3 = __shfl_xor(d3, 32);

    union { unsigned u[4]; bf16x8 v; } pa0, pa1;
    pa0.u[0] = hi ? x2 : c0;
    pa0.u[1] = hi ? x3 : c1;
    pa0.u[2] = hi ? c2 : x0;
    pa0.u[3] = hi ? c3 : x1;
    pa1.u[0] = hi ? y2 : d0;
    pa1.u[1] = hi ? y3 : d1;
    pa1.u[2] = hi ? d2 : y0;
    pa1.u[3] = hi ? d3 : y1;
    pa0v = pa0.v;
    pa1v = pa1.v;
}

static __device__ __forceinline__ void pv4(const bf16x8 pa0, const bf16x8 pa1,
                                           const bf16x8 (&vf)[4], f32x16& o0, f32x16& o1) {
    __builtin_amdgcn_s_setprio(1);
    o0 = MFMA32(pa0, vf[0], o0);
    o1 = MFMA32(pa0, vf[1], o1);
    o0 = MFMA32(pa1, vf[2], o0);
    o1 = MFMA32(pa1, vf[3], o1);
    __builtin_amdgcn_s_setprio(0);
}

__global__ __launch_bounds__(256, 4) void k_attn(const bf16_t* __restrict__ qa,
                                                 const bf16_t* __restrict__ ka,
                                                 const bf16_t* __restrict__ vT,
                                                 bf16_t* __restrict__ attn) {
    __shared__ float lm[2][32];
    __shared__ float ll[2][32];
    __shared__ float lo[2][2][16][64];  // [pair][o0/o1][reg][lane] = 16 KB
    const int tid = threadIdx.x;
    const int wave = tid >> 6, lane = tid & 63;
    const int l31 = lane & 31, hi = lane >> 5;
    const int pair = wave & 1;    // q-group in block
    const int thalf = wave >> 1;  // t-half
    const int bh = blockIdx.y;
    const int q0 = blockIdx.x * 64 + pair * 32;

    const bf16_t* Qp = qa + ((size_t)bh * S_ + q0) * HD_;
    const bf16_t* Kp = ka + (size_t)bh * S_ * HD_ + (size_t)thalf * 1024 * HD_;
    const bf16_t* Vp = vT + (size_t)bh * HD_ * S_ + thalf * 1024;

    bf16x8 qf[4];
    const bf16_t* qptr = Qp + l31 * HD_ + 8 * hi;
#pragma unroll
    for (int j = 0; j < 4; ++j) qf[j] = ldb8(qptr + 16 * j);

    const bf16_t* kl = Kp + l31 * HD_ + 8 * hi;
    const bf16_t* vl = Vp + l31 * S_ + 8 * hi;

    f32x16 o0 = {0.f, 0.f, 0.f, 0.f, 0.f, 0.f, 0.f, 0.f,
                 0.f, 0.f, 0.f, 0.f, 0.f, 0.f, 0.f, 0.f};
    f32x16 o1 = o0;
    float m = -1e30f, lsum = 0.f;

    bf16x8 kE[4], kO[4];
    loadK(kl, kE);

    for (int i = 0; i < 16; ++i) {
        // even tile (kE ready)
        {
            f32x16 s = qk4(kE, qf);
            loadK(kl + 32 * HD_, kO);  // prefetch odd-tile K during softmax
            bf16x8 vv[4];
            loadV(vl, vv);             // issued early; consumed after softmax
            bf16x8 pa0, pa1;
            softmax_pa(s, m, lsum, o0, o1, hi, pa0, pa1);
            pv4(pa0, pa1, vv, o0, o1);
        }
        // odd tile (kO ready)
        {
            f32x16 s = qk4(kO, qf);
            loadK(kl + 64 * HD_, kE);  // prefetch next even-tile K (last iter: dead read)
            bf16x8 vv[4];
            loadV(vl + 32, vv);
            bf16x8 pa0, pa1;
            softmax_pa(s, m, lsum, o0, o1, hi, pa0, pa1);
            pv4(pa0, pa1, vv, o0, o1);
        }
        kl += 64 * HD_;
        vl += 64;
    }

    // ---- merge t-halves: waves (p, p+2) share q-rows ----
    float lfull = lsum + __shfl_xor(lsum, 32);  // full row sum for q = l31
    if (thalf) {
        if (!hi) {
            lm[pair][l31] = m;
            ll[pair][l31] = lfull;
        }
#pragma unroll
        for (int r = 0; r < 16; ++r) {
            lo[pair][0][r][lane] = o0[r];
            lo[pair][1][r][lane] = o1[r];
        }
    }
    __syncthreads();
    if (!thalf) {
        float mb_ = lm[pair][l31];
        float lb_ = ll[pair][l31];
        float ms = fmaxf(m, mb_);
        float ca = __builtin_amdgcn_exp2f(m - ms);
        float cb = __builtin_amdgcn_exp2f(mb_ - ms);
        float invL = 1.0f / (lfull * ca + lb_ * cb);
        const int b = bh >> 4, h = bh & 15;
        bf16_t* op = attn + ((size_t)b * S_ + q0) * D_ + h * HD_;
#pragma unroll
        for (int r = 0; r < 16; ++r) {
            int q = (r & 3) + 8 * (r >> 2) + 4 * hi;
            float caq = __shfl(ca, q);
            float cbq = __shfl(cb, q);
            float invq = __shfl(invL, q);
            float O0 = (o0[r] * caq + lo[pair][0][r][lane] * cbq) * invq;
            float O1 = (o1[r] * caq + lo[pair][1][r][lane] * cbq) * invq;
            op[(size_t)q * D_ + l31] = (bf16_t)O0;
            op[(size_t)q * D_ + 32 + l31] = (bf16_t)O1;
        }
    }
}

// ---------------- GEMM2: out = attn @ w_o^T + b_o (fp32 out) ----------------
__global__ __launch_bounds__(256) void k_gemm_out(const bf16_t* __restrict__ attn,
                                                  const bf16_t* __restrict__ wob,
                                                  const float* __restrict__ bo,
                                                  float* __restrict__ out) {
    __shared__ bf16_t ldsA[128 * 32];
    __shared__ bf16_t ldsB[128 * 32];
    f32x4 acc[4][4];
    gemm_core(attn, wob, 1024, ldsA, ldsB, acc);

    const int tid = threadIdx.x;
    const int wave = tid >> 6, lane = tid & 63;
    const int g = lane >> 4, q16 = lane & 15;
    const int wm = wave >> 1, wn = wave & 1;
    const int mb = blockIdx.x * 128, nb = blockIdx.y * 128;
#pragma unroll
    for (int j = 0; j < 4; ++j) {
        int n = nb + wn * 64 + j * 16 + q16;
        float bias = bo[n];
#pragma unroll
        for (int i = 0; i < 4; ++i) {
            int m0 = mb + wm * 64 + i * 16 + 4 * g;
#pragma unroll
            for (int r = 0; r < 4; ++r)
                out[(size_t)(m0 + r) * D_ + n] = acc[i][j][r] + bias;
        }
    }
}

extern "C" void kernel_launch(void* const* d_in, const int* in_sizes, int n_in,
                              void* d_out, int out_size, void* d_ws, size_t ws_size,
                              hipStream_t stream) {
    const float* x    = (const float*)d_in[0];
    const float* rot  = (const float*)d_in[1];
    const float* wqkv = (const float*)d_in[2];
    const float* bqkv = (const float*)d_in[3];
    const float* wo   = (const float*)d_in[4];
    const float* bo   = (const float*)d_in[5];
    float* out = (float*)d_out;

    char* ws = (char*)d_ws;
    bf16_t* xb   = (bf16_t*)(ws);                        // 8 MB  [4096,1024]
    bf16_t* wqb  = (bf16_t*)(ws + ((size_t)8 << 20));    // 6 MB  [3072,1024]
    bf16_t* wob  = (bf16_t*)(ws + ((size_t)14 << 20));   // 2 MB  [1024,1024]
    bf16_t* qa   = (bf16_t*)(ws + ((size_t)16 << 20));   // 8 MB  [B,H,S,64]
    bf16_t* ka   = (bf16_t*)(ws + ((size_t)24 << 20));   // 8 MB  [B,H,S,64]
    bf16_t* vT   = (bf16_t*)(ws + ((size_t)32 << 20));   // 8 MB  [B,H,64,S]
    bf16_t* attn = (bf16_t*)(ws + ((size_t)40 << 20));   // 8 MB  [4096,1024]

    k_cvt<<<1024, 256, 0, stream>>>(x, xb, (B_ * S_ * D_) / 4);
    k_cvt<<<1024, 256, 0, stream>>>(wqkv, wqb, (3 * D_ * D_) / 4);
    k_cvt<<<1024, 256, 0, stream>>>(wo, wob, (D_ * D_) / 4);
    k_gemm_qkv<<<dim3(32, 24), 256, 0, stream>>>(xb, wqb, bqkv, rot, qa, ka, vT);
    k_attn<<<dim3(32, 32), 256, 0, stream>>>(qa, ka, vT, attn);
    k_gemm_out<<<dim3(32, 8), 256, 0, stream>>>(attn, wob, bo, out);
}

// Round 10
// 221.525 us; speedup vs baseline: 1.6888x; 1.2801x over previous
//
#include <hip/hip_runtime.h>

typedef __bf16 bf16_t;
typedef __bf16 bf16x8 __attribute__((ext_vector_type(8)));
typedef __bf16 bf16x4 __attribute__((ext_vector_type(4)));
typedef __bf16 bf16x2 __attribute__((ext_vector_type(2)));
typedef float f32x4 __attribute__((ext_vector_type(4)));
typedef float f32x16 __attribute__((ext_vector_type(16)));

#define B_ 2
#define S_ 2048
#define D_ 1024
#define H_ 16
#define HD_ 64

#define MFMA(a, b, c) __builtin_amdgcn_mfma_f32_16x16x32_bf16(a, b, c, 0, 0, 0)
#define MFMA32(a, b, c) __builtin_amdgcn_mfma_f32_32x32x16_bf16(a, b, c, 0, 0, 0)

static __device__ __forceinline__ bf16x8 ldb8(const bf16_t* p) {
    return *(const bf16x8*)p;
}

static __device__ __forceinline__ void gload16(const void* g, void* l) {
    __builtin_amdgcn_global_load_lds((const __attribute__((address_space(1))) void*)g,
                                     (__attribute__((address_space(3))) void*)l, 16, 0, 0);
}

static __device__ __forceinline__ unsigned cvtpk(float a, float b) {
    union { bf16x2 h; unsigned u; } cv;
    cv.h[0] = (bf16_t)a;
    cv.h[1] = (bf16_t)b;
    return cv.u;
}
static __device__ __forceinline__ float xhalf_max(float x) {
    return fmaxf(x, __shfl_xor(x, 32));
}

// ---------------- fp32 -> bf16 convert ----------------
__global__ __launch_bounds__(256) void k_cvt(const float* __restrict__ in,
                                             bf16_t* __restrict__ out, int n4) {
    int i = blockIdx.x * 256 + threadIdx.x;
    int stride = gridDim.x * 256;
    for (; i < n4; i += stride) {
        float4 v = ((const float4*)in)[i];
        bf16x4 o;
        o[0] = (bf16_t)v.x; o[1] = (bf16_t)v.y; o[2] = (bf16_t)v.z; o[3] = (bf16_t)v.w;
        ((bf16x4*)out)[i] = o;
    }
}

// ---------------- shared GEMM main loop (C = A * Bt^T), 128x128 tile, BK=32 ----
static __device__ __forceinline__ void gemm_core(const bf16_t* __restrict__ A,
                                                 const bf16_t* __restrict__ Bt,
                                                 const int K, bf16_t* ldsA, bf16_t* ldsB,
                                                 f32x4 acc[4][4]) {
    const int tid = threadIdx.x;
    const int wave = tid >> 6, lane = tid & 63;
    const int g = lane >> 4, q16 = lane & 15;
    const int wm = wave >> 1, wn = wave & 1;
    const int mb = blockIdx.x * 128, nb = blockIdx.y * 128;
    const int r0 = lane >> 2, c8 = (lane & 3) * 8;

#pragma unroll
    for (int i = 0; i < 4; ++i)
#pragma unroll
        for (int j = 0; j < 4; ++j) {
            f32x4 z = {0.f, 0.f, 0.f, 0.f};
            acc[i][j] = z;
        }

    const bf16_t* ga0 = A + (size_t)(mb + wave * 16 + r0) * K + c8;
    const bf16_t* ga1 = A + (size_t)(mb + 64 + wave * 16 + r0) * K + c8;
    const bf16_t* gb0 = Bt + (size_t)(nb + wave * 16 + r0) * K + c8;
    const bf16_t* gb1 = Bt + (size_t)(nb + 64 + wave * 16 + r0) * K + c8;
    bf16_t* la0 = ldsA + (wave * 16) * 32;
    bf16_t* la1 = ldsA + (64 + wave * 16) * 32;
    bf16_t* lb0 = ldsB + (wave * 16) * 32;
    bf16_t* lb1 = ldsB + (64 + wave * 16) * 32;

    for (int k0 = 0; k0 < K; k0 += 32) {
        gload16(ga0 + k0, la0);
        gload16(ga1 + k0, la1);
        gload16(gb0 + k0, lb0);
        gload16(gb1 + k0, lb1);
        __syncthreads();
        bf16x8 af[4], bfv[4];
#pragma unroll
        for (int i = 0; i < 4; ++i)
            af[i] = ldb8(ldsA + (wm * 64 + i * 16 + q16) * 32 + 8 * g);
#pragma unroll
        for (int j = 0; j < 4; ++j)
            bfv[j] = ldb8(ldsB + (wn * 64 + j * 16 + q16) * 32 + 8 * g);
#pragma unroll
        for (int i = 0; i < 4; ++i)
#pragma unroll
            for (int j = 0; j < 4; ++j)
                acc[i][j] = MFMA(af[i], bfv[j], acc[i][j]);
        __syncthreads();
    }
}

// ---------------- GEMM1: qkv = x @ w_qkv^T + b, fused RoPE ----------------
// K and V are written in MFMA-fragment-native TILED layouts so the attention
// kernel's fragment loads are fully coalesced (round-9 lesson: row-strided
// fragment loads saturate the texture-addresser at ~400 line-tx/tile/wave).
// K tiled: elem(t,hd) -> [bh][t>>5] tile of 2048 elems, idx =
//   (hd>>4)*512 + (t&31)*16 + ((hd>>3)&1)*8 + (hd&7)
// V tiled: elem(t,hd) -> [bh][t>>5] tile, x = ((t>>4)&1)*2 + (hd>>5), idx =
//   x*512 + (hd&31)*16 + ((t>>3)&1)*8 + (t&7)
__global__ __launch_bounds__(256) void k_gemm_qkv(const bf16_t* __restrict__ xb,
                                                  const bf16_t* __restrict__ wqb,
                                                  const float* __restrict__ bqkv,
                                                  const float* __restrict__ rot,
                                                  bf16_t* __restrict__ qa,
                                                  bf16_t* __restrict__ kt,
                                                  bf16_t* __restrict__ vt) {
    __shared__ bf16_t ldsA[128 * 32];
    __shared__ bf16_t ldsB[128 * 32];
    f32x4 acc[4][4];
    gemm_core(xb, wqb, 1024, ldsA, ldsB, acc);

    const int tid = threadIdx.x;
    const int wave = tid >> 6, lane = tid & 63;
    const int g = lane >> 4, q16 = lane & 15;
    const int wm = wave >> 1, wn = wave & 1;
    const int mb = blockIdx.x * 128, nb = blockIdx.y * 128;
    const int third = nb >> 10;  // 0=q, 1=k, 2=v
    const float QS = 0.125f * 1.44269504088896f;  // softmax scale * log2(e)

    if (third < 2) {
        const float2* cs2 = (const float2*)rot;
#pragma unroll
        for (int j = 0; j < 4; ++j) {
            int n = nb + wn * 64 + j * 16 + q16;
            float bias = bqkv[n];
            int d = n & 1023;
            int h = d >> 6, hd = d & 63;
            int i2 = hd >> 1;
            bool odd = (hd & 1) != 0;
#pragma unroll
            for (int i = 0; i < 4; ++i) {
                int m0 = mb + wm * 64 + i * 16 + 4 * g;
#pragma unroll
                for (int r = 0; r < 4; ++r) {
                    int mm = m0 + r;
                    int s = mm & 2047, b = mm >> 11;
                    float val = acc[i][j][r] + bias;
                    float prt = __shfl_xor(val, 1);
                    float2 cs = cs2[s * 32 + i2];
                    float rv = val * cs.x + (odd ? prt * cs.y : -(prt * cs.y));
                    size_t base = (size_t)(b * H_ + h) * (S_ * 64);
                    if (third == 0) {
                        qa[base + (size_t)s * HD_ + hd] = (bf16_t)(rv * QS);
                    } else {
                        int idx = ((s >> 5) << 11) + ((hd >> 4) << 9) + ((s & 31) << 4)
                                + (((hd >> 3) & 1) << 3) + (hd & 7);
                        kt[base + idx] = (bf16_t)rv;
                    }
                }
            }
        }
    } else {
#pragma unroll
        for (int j = 0; j < 4; ++j) {
            int n = nb + wn * 64 + j * 16 + q16;
            float bias = bqkv[n];
            int d = n & 1023;
            int h = d >> 6, hd = d & 63;
#pragma unroll
            for (int i = 0; i < 4; ++i) {
                int m0 = mb + wm * 64 + i * 16 + 4 * g;
                int s0 = m0 & 2047, b = m0 >> 11;
                bf16x4 pk;
#pragma unroll
                for (int r = 0; r < 4; ++r) pk[r] = (bf16_t)(acc[i][j][r] + bias);
                int x = (((s0 >> 4) & 1) << 1) + (hd >> 5);
                size_t base = (size_t)(b * H_ + h) * (S_ * 64);
                size_t idx = ((size_t)(s0 >> 5) << 11) + (x << 9) + ((hd & 31) << 4)
                           + (((s0 >> 3) & 1) << 3) + (s0 & 7);
                *(bf16x4*)(vt + base + idx) = pk;
            }
        }
    }
}

// ---------------- flash attention ----------------
// In-block t-split: 4 waves; waves (p, p+2) share 32 q-rows (p=wave&1), cover
// t-halves [0,1024)/[1024,2048); exact online-softmax merge via LDS epilogue.
// K/V read from fragment-native tiled layouts: each frag load is 16B/lane at
// base + 16B*(2*l31+hi) -> fully coalesced (8 lines/instr vs 32-64 before).
static __device__ __forceinline__ void loadK(const bf16_t* kbase, bf16x8 (&kf)[4]) {
#pragma unroll
    for (int j = 0; j < 4; ++j) kf[j] = ldb8(kbase + 512 * j);
}
static __device__ __forceinline__ void loadV(const bf16_t* vbase, bf16x8 (&vf)[4]) {
    vf[0] = ldb8(vbase);
    vf[1] = ldb8(vbase + 512);
    vf[2] = ldb8(vbase + 1024);
    vf[3] = ldb8(vbase + 1536);
}

static __device__ __forceinline__ f32x16 qk4(const bf16x8 (&kf)[4], const bf16x8 (&qf)[4]) {
    f32x16 s = {0.f, 0.f, 0.f, 0.f, 0.f, 0.f, 0.f, 0.f,
                0.f, 0.f, 0.f, 0.f, 0.f, 0.f, 0.f, 0.f};
    __builtin_amdgcn_s_setprio(1);
#pragma unroll
    for (int j = 0; j < 4; ++j) s = MFMA32(kf[j], qf[j], s);
    __builtin_amdgcn_s_setprio(0);
    return s;
}

static __device__ __forceinline__ void softmax_pa(f32x16& s, float& m, float& lsum,
                                                  f32x16& o0, f32x16& o1,
                                                  int hi, bf16x8& pa0v, bf16x8& pa1v) {
    float a0 = fmaxf(fmaxf(s[0], s[1]), s[2]);
    float a1 = fmaxf(fmaxf(s[3], s[4]), s[5]);
    float a2 = fmaxf(fmaxf(s[6], s[7]), s[8]);
    float a3 = fmaxf(fmaxf(s[9], s[10]), s[11]);
    float a4 = fmaxf(fmaxf(s[12], s[13]), s[14]);
    float tm = fmaxf(fmaxf(fmaxf(a0, a1), a2), fmaxf(fmaxf(a3, a4), s[15]));
    tm = xhalf_max(tm);  // lane^32 shares the q-row

    bool ok = (tm <= m + 8.0f);  // defer-max threshold (exp2 domain)
    if (!__all(ok)) {
        float mn = fmaxf(m, tm);
        float ce = __builtin_amdgcn_exp2f(m - mn);
        m = mn;
        lsum *= ce;
#pragma unroll
        for (int r = 0; r < 16; ++r) {
            int q = (r & 3) + 8 * (r >> 2) + 4 * hi;
            float c = __shfl(ce, q);
            o0[r] *= c; o1[r] *= c;
        }
    }

#pragma unroll
    for (int r = 0; r < 16; ++r) s[r] = __builtin_amdgcn_exp2f(s[r] - m);
    float ps = (((s[0] + s[1]) + (s[2] + s[3])) + ((s[4] + s[5]) + (s[6] + s[7])))
             + (((s[8] + s[9]) + (s[10] + s[11])) + ((s[12] + s[13]) + (s[14] + s[15])));
    lsum += ps;

    unsigned c0 = cvtpk(s[0], s[1]),   c1 = cvtpk(s[2], s[3]);
    unsigned c2 = cvtpk(s[4], s[5]),   c3 = cvtpk(s[6], s[7]);
    unsigned d0 = cvtpk(s[8], s[9]),   d1 = cvtpk(s[10], s[11]);
    unsigned d2 = cvtpk(s[12], s[13]), d3 = cvtpk(s[14], s[15]);
    unsigned x0 = __shfl_xor(c0, 32), x1 = __shfl_xor(c1, 32);
    unsigned x2 = __shfl_xor(c2, 32), x3 = __shfl_xor(c3, 32);
    unsigned y0 = __shfl_xor(d0, 32), y1 = __shfl_xor(d1, 32);
    unsigned y2 = __shfl_xor(d2, 32), y3 = __shfl_xor(d3, 32);

    union { unsigned u[4]; bf16x8 v; } pa0, pa1;
    pa0.u[0] = hi ? x2 : c0;
    pa0.u[1] = hi ? x3 : c1;
    pa0.u[2] = hi ? c2 : x0;
    pa0.u[3] = hi ? c3 : x1;
    pa1.u[0] = hi ? y2 : d0;
    pa1.u[1] = hi ? y3 : d1;
    pa1.u[2] = hi ? d2 : y0;
    pa1.u[3] = hi ? d3 : y1;
    pa0v = pa0.v;
    pa1v = pa1.v;
}

static __device__ __forceinline__ void pv4(const bf16x8 pa0, const bf16x8 pa1,
                                           const bf16x8 (&vf)[4], f32x16& o0, f32x16& o1) {
    __builtin_amdgcn_s_setprio(1);
    o0 = MFMA32(pa0, vf[0], o0);
    o1 = MFMA32(pa0, vf[1], o1);
    o0 = MFMA32(pa1, vf[2], o0);
    o1 = MFMA32(pa1, vf[3], o1);
    __builtin_amdgcn_s_setprio(0);
}

__global__ __launch_bounds__(256, 4) void k_attn(const bf16_t* __restrict__ qa,
                                                 const bf16_t* __restrict__ kt,
                                                 const bf16_t* __restrict__ vt,
                                                 bf16_t* __restrict__ attn) {
    __shared__ float lm[2][32];
    __shared__ float ll[2][32];
    __shared__ float lo[2][2][16][64];  // [pair][o0/o1][reg][lane] = 16 KB
    const int tid = threadIdx.x;
    const int wave = tid >> 6, lane = tid & 63;
    const int l31 = lane & 31, hi = lane >> 5;
    const int pair = wave & 1;    // q-group in block
    const int thalf = wave >> 1;  // t-half
    const int bh = blockIdx.y;
    const int q0 = blockIdx.x * 64 + pair * 32;

    const bf16_t* Qp = qa + ((size_t)bh * S_ + q0) * HD_;
    const int laneoff = (2 * l31 + hi) * 8;
    const bf16_t* kl = kt + (size_t)bh * (S_ * 64) + (size_t)thalf * 65536 + laneoff;
    const bf16_t* vl = vt + (size_t)bh * (S_ * 64) + (size_t)thalf * 65536 + laneoff;

    bf16x8 qf[4];
    const bf16_t* qptr = Qp + l31 * HD_ + 8 * hi;
#pragma unroll
    for (int j = 0; j < 4; ++j) qf[j] = ldb8(qptr + 16 * j);

    f32x16 o0 = {0.f, 0.f, 0.f, 0.f, 0.f, 0.f, 0.f, 0.f,
                 0.f, 0.f, 0.f, 0.f, 0.f, 0.f, 0.f, 0.f};
    f32x16 o1 = o0;
    float m = -1e30f, lsum = 0.f;

    bf16x8 kE[4], kO[4];
    loadK(kl, kE);

    for (int i = 0; i < 16; ++i) {
        // even tile (kE ready)
        {
            f32x16 s = qk4(kE, qf);
            loadK(kl + 2048, kO);  // prefetch odd-tile K during softmax
            bf16x8 vv[4];
            loadV(vl, vv);         // issued early; consumed after softmax
            bf16x8 pa0, pa1;
            softmax_pa(s, m, lsum, o0, o1, hi, pa0, pa1);
            pv4(pa0, pa1, vv, o0, o1);
        }
        // odd tile (kO ready)
        {
            f32x16 s = qk4(kO, qf);
            loadK(kl + 4096, kE);  // prefetch next even-tile K (last iter: dead read)
            bf16x8 vv[4];
            loadV(vl + 2048, vv);
            bf16x8 pa0, pa1;
            softmax_pa(s, m, lsum, o0, o1, hi, pa0, pa1);
            pv4(pa0, pa1, vv, o0, o1);
        }
        kl += 4096;
        vl += 4096;
    }

    // ---- merge t-halves: waves (p, p+2) share q-rows ----
    float lfull = lsum + __shfl_xor(lsum, 32);  // full row sum for q = l31
    if (thalf) {
        if (!hi) {
            lm[pair][l31] = m;
            ll[pair][l31] = lfull;
        }
#pragma unroll
        for (int r = 0; r < 16; ++r) {
            lo[pair][0][r][lane] = o0[r];
            lo[pair][1][r][lane] = o1[r];
        }
    }
    __syncthreads();
    if (!thalf) {
        float mb_ = lm[pair][l31];
        float lb_ = ll[pair][l31];
        float ms = fmaxf(m, mb_);
        float ca = __builtin_amdgcn_exp2f(m - ms);
        float cb = __builtin_amdgcn_exp2f(mb_ - ms);
        float invL = 1.0f / (lfull * ca + lb_ * cb);
        const int b = bh >> 4, h = bh & 15;
        bf16_t* op = attn + ((size_t)b * S_ + q0) * D_ + h * HD_;
#pragma unroll
        for (int r = 0; r < 16; ++r) {
            int q = (r & 3) + 8 * (r >> 2) + 4 * hi;
            float caq = __shfl(ca, q);
            float cbq = __shfl(cb, q);
            float invq = __shfl(invL, q);
            float O0 = (o0[r] * caq + lo[pair][0][r][lane] * cbq) * invq;
            float O1 = (o1[r] * caq + lo[pair][1][r][lane] * cbq) * invq;
            op[(size_t)q * D_ + l31] = (bf16_t)O0;
            op[(size_t)q * D_ + 32 + l31] = (bf16_t)O1;
        }
    }
}

// ---------------- GEMM2: out = attn @ w_o^T + b_o (fp32 out) ----------------
__global__ __launch_bounds__(256) void k_gemm_out(const bf16_t* __restrict__ attn,
                                                  const bf16_t* __restrict__ wob,
                                                  const float* __restrict__ bo,
                                                  float* __restrict__ out) {
    __shared__ bf16_t ldsA[128 * 32];
    __shared__ bf16_t ldsB[128 * 32];
    f32x4 acc[4][4];
    gemm_core(attn, wob, 1024, ldsA, ldsB, acc);

    const int tid = threadIdx.x;
    const int wave = tid >> 6, lane = tid & 63;
    const int g = lane >> 4, q16 = lane & 15;
    const int wm = wave >> 1, wn = wave & 1;
    const int mb = blockIdx.x * 128, nb = blockIdx.y * 128;
#pragma unroll
    for (int j = 0; j < 4; ++j) {
        int n = nb + wn * 64 + j * 16 + q16;
        float bias = bo[n];
#pragma unroll
        for (int i = 0; i < 4; ++i) {
            int m0 = mb + wm * 64 + i * 16 + 4 * g;
#pragma unroll
            for (int r = 0; r < 4; ++r)
                out[(size_t)(m0 + r) * D_ + n] = acc[i][j][r] + bias;
        }
    }
}

extern "C" void kernel_launch(void* const* d_in, const int* in_sizes, int n_in,
                              void* d_out, int out_size, void* d_ws, size_t ws_size,
                              hipStream_t stream) {
    const float* x    = (const float*)d_in[0];
    const float* rot  = (const float*)d_in[1];
    const float* wqkv = (const float*)d_in[2];
    const float* bqkv = (const float*)d_in[3];
    const float* wo   = (const float*)d_in[4];
    const float* bo   = (const float*)d_in[5];
    float* out = (float*)d_out;

    char* ws = (char*)d_ws;
    bf16_t* xb   = (bf16_t*)(ws);                        // 8 MB  [4096,1024]
    bf16_t* wqb  = (bf16_t*)(ws + ((size_t)8 << 20));    // 6 MB  [3072,1024]
    bf16_t* wob  = (bf16_t*)(ws + ((size_t)14 << 20));   // 2 MB  [1024,1024]
    bf16_t* qa   = (bf16_t*)(ws + ((size_t)16 << 20));   // 8 MB  [B,H,S,64]
    bf16_t* kt   = (bf16_t*)(ws + ((size_t)24 << 20));   // 8 MB  K tiled
    bf16_t* vt   = (bf16_t*)(ws + ((size_t)32 << 20));   // 8 MB  V tiled
    bf16_t* attn = (bf16_t*)(ws + ((size_t)40 << 20));   // 8 MB  [4096,1024]

    k_cvt<<<1024, 256, 0, stream>>>(x, xb, (B_ * S_ * D_) / 4);
    k_cvt<<<1024, 256, 0, stream>>>(wqkv, wqb, (3 * D_ * D_) / 4);
    k_cvt<<<1024, 256, 0, stream>>>(wo, wob, (D_ * D_) / 4);
    k_gemm_qkv<<<dim3(32, 24), 256, 0, stream>>>(xb, wqb, bqkv, rot, qa, kt, vt);
    k_attn<<<dim3(32, 32), 256, 0, stream>>>(qa, kt, vt, attn);
    k_gemm_out<<<dim3(32, 8), 256, 0, stream>>>(attn, wob, bo, out);
}

// Round 11
// 202.040 us; speedup vs baseline: 1.8517x; 1.0964x over previous
//
#include <hip/hip_runtime.h>

typedef __bf16 bf16_t;
typedef __bf16 bf16x8 __attribute__((ext_vector_type(8)));
typedef __bf16 bf16x4 __attribute__((ext_vector_type(4)));
typedef __bf16 bf16x2 __attribute__((ext_vector_type(2)));
typedef float f32x4 __attribute__((ext_vector_type(4)));
typedef float f32x16 __attribute__((ext_vector_type(16)));

#define B_ 2
#define S_ 2048
#define D_ 1024
#define H_ 16
#define HD_ 64

#define MFMA(a, b, c) __builtin_amdgcn_mfma_f32_16x16x32_bf16(a, b, c, 0, 0, 0)
#define MFMA32(a, b, c) __builtin_amdgcn_mfma_f32_32x32x16_bf16(a, b, c, 0, 0, 0)

static __device__ __forceinline__ bf16x8 ldb8(const bf16_t* p) {
    return *(const bf16x8*)p;
}

static __device__ __forceinline__ void gload16(const void* g, void* l) {
    __builtin_amdgcn_global_load_lds((const __attribute__((address_space(1))) void*)g,
                                     (__attribute__((address_space(3))) void*)l, 16, 0, 0);
}

static __device__ __forceinline__ unsigned cvtpk(float a, float b) {
    union { bf16x2 h; unsigned u; } cv;
    cv.h[0] = (bf16_t)a;
    cv.h[1] = (bf16_t)b;
    return cv.u;
}
static __device__ __forceinline__ float xhalf_max(float x) {
    return fmaxf(x, __shfl_xor(x, 32));
}

// ---------------- fused fp32 -> bf16 convert (x, w_qkv, w_o in one launch) ----
#define N4_X  1048576
#define N4_WQ 786432
#define N4_WO 262144
__global__ __launch_bounds__(256) void k_cvt3(const float* __restrict__ x,
                                              const float* __restrict__ wq,
                                              const float* __restrict__ wo,
                                              bf16_t* __restrict__ xb,
                                              bf16_t* __restrict__ wqb,
                                              bf16_t* __restrict__ wob) {
    int i = blockIdx.x * 256 + threadIdx.x;
    int stride = gridDim.x * 256;
    for (; i < N4_X + N4_WQ + N4_WO; i += stride) {
        const float4* src;
        bf16x4* dst;
        int off;
        if (i < N4_X) {
            src = (const float4*)x; dst = (bf16x4*)xb; off = i;
        } else if (i < N4_X + N4_WQ) {
            src = (const float4*)wq; dst = (bf16x4*)wqb; off = i - N4_X;
        } else {
            src = (const float4*)wo; dst = (bf16x4*)wob; off = i - (N4_X + N4_WQ);
        }
        float4 v = src[off];
        bf16x4 o;
        o[0] = (bf16_t)v.x; o[1] = (bf16_t)v.y; o[2] = (bf16_t)v.z; o[3] = (bf16_t)v.w;
        dst[off] = o;
    }
}

// ---------------- shared GEMM main loop (C = A * Bt^T), 128x128 tile, BK=32 ----
// mb = row-tile base into A, nb = row-tile base into Bt.
static __device__ __forceinline__ void gemm_core(const bf16_t* __restrict__ A,
                                                 const bf16_t* __restrict__ Bt,
                                                 const int K, bf16_t* ldsA, bf16_t* ldsB,
                                                 f32x4 acc[4][4], int mb, int nb) {
    const int tid = threadIdx.x;
    const int wave = tid >> 6, lane = tid & 63;
    const int g = lane >> 4, q16 = lane & 15;
    const int wm = wave >> 1, wn = wave & 1;
    const int r0 = lane >> 2, c8 = (lane & 3) * 8;

#pragma unroll
    for (int i = 0; i < 4; ++i)
#pragma unroll
        for (int j = 0; j < 4; ++j) {
            f32x4 z = {0.f, 0.f, 0.f, 0.f};
            acc[i][j] = z;
        }

    const bf16_t* ga0 = A + (size_t)(mb + wave * 16 + r0) * K + c8;
    const bf16_t* ga1 = A + (size_t)(mb + 64 + wave * 16 + r0) * K + c8;
    const bf16_t* gb0 = Bt + (size_t)(nb + wave * 16 + r0) * K + c8;
    const bf16_t* gb1 = Bt + (size_t)(nb + 64 + wave * 16 + r0) * K + c8;
    bf16_t* la0 = ldsA + (wave * 16) * 32;
    bf16_t* la1 = ldsA + (64 + wave * 16) * 32;
    bf16_t* lb0 = ldsB + (wave * 16) * 32;
    bf16_t* lb1 = ldsB + (64 + wave * 16) * 32;

    for (int k0 = 0; k0 < K; k0 += 32) {
        gload16(ga0 + k0, la0);
        gload16(ga1 + k0, la1);
        gload16(gb0 + k0, lb0);
        gload16(gb1 + k0, lb1);
        __syncthreads();
        bf16x8 af[4], bfv[4];
#pragma unroll
        for (int i = 0; i < 4; ++i)
            af[i] = ldb8(ldsA + (wm * 64 + i * 16 + q16) * 32 + 8 * g);
#pragma unroll
        for (int j = 0; j < 4; ++j)
            bfv[j] = ldb8(ldsB + (wn * 64 + j * 16 + q16) * 32 + 8 * g);
#pragma unroll
        for (int i = 0; i < 4; ++i)
#pragma unroll
            for (int j = 0; j < 4; ++j)
                acc[i][j] = MFMA(af[i], bfv[j], acc[i][j]);
        __syncthreads();
    }
}

// ---------------- GEMM1: qkv = x @ w_qkv^T + b, fused RoPE ----------------
// Q/K blocks run the GEMM TRANSPOSED (A = w_qkv rows, Bt = x rows) so each
// lane's 4 acc elements are CONSECUTIVE hd: RoPE pairs are lane-local (no
// shuffles), bias/rot are float4 loads, stores are bf16x4 (round-10 lesson:
// 64 scalar stores + 64 shfl per thread dominated the epilogue).
// K tiled layout: elem(t,hd) -> tile t>>5 (2048 elems), idx =
//   (hd>>4)*512 + (t&31)*16 + ((hd>>3)&1)*8 + (hd&7)
// V tiled layout: elem(t,hd) -> tile t>>5, x = ((t>>4)&1)*2 + (hd>>5), idx =
//   x*512 + (hd&31)*16 + ((t>>3)&1)*8 + (t&7)
__global__ __launch_bounds__(256) void k_gemm_qkv(const bf16_t* __restrict__ xb,
                                                  const bf16_t* __restrict__ wqb,
                                                  const float* __restrict__ bqkv,
                                                  const float* __restrict__ rot,
                                                  bf16_t* __restrict__ qa,
                                                  bf16_t* __restrict__ kt,
                                                  bf16_t* __restrict__ vt) {
    __shared__ bf16_t ldsA[128 * 32];
    __shared__ bf16_t ldsB[128 * 32];
    const int tid = threadIdx.x;
    const int wave = tid >> 6, lane = tid & 63;
    const int g = lane >> 4, q16 = lane & 15;
    const int wm = wave >> 1, wn = wave & 1;
    const int sx = blockIdx.x;          // token tile (128 tokens)
    const int third = blockIdx.y >> 3;  // 0=q, 1=k, 2=v
    const int ny = blockIdx.y & 7;      // feature tile within third
    const float QS = 0.125f * 1.44269504088896f;  // softmax scale * log2(e)
    f32x4 acc[4][4];

    if (third < 2) {
        // transposed: acc row = feature n, col = token s
        gemm_core(wqb, xb, 1024, ldsA, ldsB, acc, third * 1024 + ny * 128, sx * 128);
        const int h = ny * 2 + wm;
#pragma unroll
        for (int i = 0; i < 4; ++i) {
            const int hdb = i * 16 + 4 * g;  // hd base (consecutive 4 via acc regs)
            float4 bi = *(const float4*)&bqkv[third * 1024 + ny * 128 + wm * 64 + hdb];
#pragma unroll
            for (int j = 0; j < 4; ++j) {
                int mm = sx * 128 + wn * 64 + j * 16 + q16;
                int s = mm & 2047, b = mm >> 11;
                float4 cs = *(const float4*)&rot[s * 64 + hdb];  // (c0,s0,c1,s1)
                float v0 = acc[i][j][0] + bi.x, v1 = acc[i][j][1] + bi.y;
                float v2 = acc[i][j][2] + bi.z, v3 = acc[i][j][3] + bi.w;
                float r0 = v0 * cs.x - v1 * cs.y, r1 = v0 * cs.y + v1 * cs.x;
                float r2 = v2 * cs.z - v3 * cs.w, r3 = v2 * cs.w + v3 * cs.z;
                size_t base = (size_t)(b * H_ + h) * (S_ * 64);
                bf16x4 pk;
                if (third == 0) {
                    pk[0] = (bf16_t)(r0 * QS); pk[1] = (bf16_t)(r1 * QS);
                    pk[2] = (bf16_t)(r2 * QS); pk[3] = (bf16_t)(r3 * QS);
                    *(bf16x4*)(qa + base + (size_t)s * HD_ + hdb) = pk;
                } else {
                    pk[0] = (bf16_t)r0; pk[1] = (bf16_t)r1;
                    pk[2] = (bf16_t)r2; pk[3] = (bf16_t)r3;
                    size_t idx = ((size_t)(s >> 5) << 11) + (i << 9) + ((s & 31) << 4)
                               + ((g >> 1) << 3) + ((g & 1) << 2);
                    *(bf16x4*)(kt + base + idx) = pk;
                }
            }
        }
    } else {
        // untransposed: acc row = token s, col = feature n (vt wants s-contig)
        gemm_core(xb, wqb, 1024, ldsA, ldsB, acc, sx * 128, 2048 + ny * 128);
#pragma unroll
        for (int j = 0; j < 4; ++j) {
            int n = 2048 + ny * 128 + wn * 64 + j * 16 + q16;
            float bias = bqkv[n];
            int d = n & 1023;
            int h = d >> 6, hd = d & 63;
#pragma unroll
            for (int i = 0; i < 4; ++i) {
                int m0 = sx * 128 + wm * 64 + i * 16 + 4 * g;
                int s0 = m0 & 2047, b = m0 >> 11;
                bf16x4 pk;
#pragma unroll
                for (int r = 0; r < 4; ++r) pk[r] = (bf16_t)(acc[i][j][r] + bias);
                int x = (((s0 >> 4) & 1) << 1) + (hd >> 5);
                size_t base = (size_t)(b * H_ + h) * (S_ * 64);
                size_t idx = ((size_t)(s0 >> 5) << 11) + (x << 9) + ((hd & 31) << 4)
                           + (((s0 >> 3) & 1) << 3) + (s0 & 7);
                *(bf16x4*)(vt + base + idx) = pk;
            }
        }
    }
}

// ---------------- flash attention ----------------
// In-block t-split: 4 waves; waves (p, p+2) share 32 q-rows (p=wave&1), cover
// t-halves [0,1024)/[1024,2048); exact online-softmax merge via LDS epilogue.
// K/V read from fragment-native tiled layouts: each frag load is 16B/lane at
// base + 16B*(2*l31+hi) -> fully coalesced (8 lines/instr vs 32-64 before).
static __device__ __forceinline__ void loadK(const bf16_t* kbase, bf16x8 (&kf)[4]) {
#pragma unroll
    for (int j = 0; j < 4; ++j) kf[j] = ldb8(kbase + 512 * j);
}
static __device__ __forceinline__ void loadV(const bf16_t* vbase, bf16x8 (&vf)[4]) {
    vf[0] = ldb8(vbase);
    vf[1] = ldb8(vbase + 512);
    vf[2] = ldb8(vbase + 1024);
    vf[3] = ldb8(vbase + 1536);
}

static __device__ __forceinline__ f32x16 qk4(const bf16x8 (&kf)[4], const bf16x8 (&qf)[4]) {
    f32x16 s = {0.f, 0.f, 0.f, 0.f, 0.f, 0.f, 0.f, 0.f,
                0.f, 0.f, 0.f, 0.f, 0.f, 0.f, 0.f, 0.f};
    __builtin_amdgcn_s_setprio(1);
#pragma unroll
    for (int j = 0; j < 4; ++j) s = MFMA32(kf[j], qf[j], s);
    __builtin_amdgcn_s_setprio(0);
    return s;
}

static __device__ __forceinline__ void softmax_pa(f32x16& s, float& m, float& lsum,
                                                  f32x16& o0, f32x16& o1,
                                                  int hi, bf16x8& pa0v, bf16x8& pa1v) {
    float a0 = fmaxf(fmaxf(s[0], s[1]), s[2]);
    float a1 = fmaxf(fmaxf(s[3], s[4]), s[5]);
    float a2 = fmaxf(fmaxf(s[6], s[7]), s[8]);
    float a3 = fmaxf(fmaxf(s[9], s[10]), s[11]);
    float a4 = fmaxf(fmaxf(s[12], s[13]), s[14]);
    float tm = fmaxf(fmaxf(fmaxf(a0, a1), a2), fmaxf(fmaxf(a3, a4), s[15]));
    tm = xhalf_max(tm);  // lane^32 shares the q-row

    bool ok = (tm <= m + 8.0f);  // defer-max threshold (exp2 domain)
    if (!__all(ok)) {
        float mn = fmaxf(m, tm);
        float ce = __builtin_amdgcn_exp2f(m - mn);
        m = mn;
        lsum *= ce;
#pragma unroll
        for (int r = 0; r < 16; ++r) {
            int q = (r & 3) + 8 * (r >> 2) + 4 * hi;
            float c = __shfl(ce, q);
            o0[r] *= c; o1[r] *= c;
        }
    }

#pragma unroll
    for (int r = 0; r < 16; ++r) s[r] = __builtin_amdgcn_exp2f(s[r] - m);
    float ps = (((s[0] + s[1]) + (s[2] + s[3])) + ((s[4] + s[5]) + (s[6] + s[7])))
             + (((s[8] + s[9]) + (s[10] + s[11])) + ((s[12] + s[13]) + (s[14] + s[15])));
    lsum += ps;

    unsigned c0 = cvtpk(s[0], s[1]),   c1 = cvtpk(s[2], s[3]);
    unsigned c2 = cvtpk(s[4], s[5]),   c3 = cvtpk(s[6], s[7]);
    unsigned d0 = cvtpk(s[8], s[9]),   d1 = cvtpk(s[10], s[11]);
    unsigned d2 = cvtpk(s[12], s[13]), d3 = cvtpk(s[14], s[15]);
    unsigned x0 = __shfl_xor(c0, 32), x1 = __shfl_xor(c1, 32);
    unsigned x2 = __shfl_xor(c2, 32), x3 = __shfl_xor(c3, 32);
    unsigned y0 = __shfl_xor(d0, 32), y1 = __shfl_xor(d1, 32);
    unsigned y2 = __shfl_xor(d2, 32), y3 = __shfl_xor(d3, 32);

    union { unsigned u[4]; bf16x8 v; } pa0, pa1;
    pa0.u[0] = hi ? x2 : c0;
    pa0.u[1] = hi ? x3 : c1;
    pa0.u[2] = hi ? c2 : x0;
    pa0.u[3] = hi ? c3 : x1;
    pa1.u[0] = hi ? y2 : d0;
    pa1.u[1] = hi ? y3 : d1;
    pa1.u[2] = hi ? d2 : y0;
    pa1.u[3] = hi ? d3 : y1;
    pa0v = pa0.v;
    pa1v = pa1.v;
}

static __device__ __forceinline__ void pv4(const bf16x8 pa0, const bf16x8 pa1,
                                           const bf16x8 (&vf)[4], f32x16& o0, f32x16& o1) {
    __builtin_amdgcn_s_setprio(1);
    o0 = MFMA32(pa0, vf[0], o0);
    o1 = MFMA32(pa0, vf[1], o1);
    o0 = MFMA32(pa1, vf[2], o0);
    o1 = MFMA32(pa1, vf[3], o1);
    __builtin_amdgcn_s_setprio(0);
}

__global__ __launch_bounds__(256, 4) void k_attn(const bf16_t* __restrict__ qa,
                                                 const bf16_t* __restrict__ kt,
                                                 const bf16_t* __restrict__ vt,
                                                 bf16_t* __restrict__ attn) {
    __shared__ float lm[2][32];
    __shared__ float ll[2][32];
    __shared__ float lo[2][2][16][64];  // [pair][o0/o1][reg][lane] = 16 KB
    const int tid = threadIdx.x;
    const int wave = tid >> 6, lane = tid & 63;
    const int l31 = lane & 31, hi = lane >> 5;
    const int pair = wave & 1;    // q-group in block
    const int thalf = wave >> 1;  // t-half
    const int bh = blockIdx.y;
    const int q0 = blockIdx.x * 64 + pair * 32;

    const bf16_t* Qp = qa + ((size_t)bh * S_ + q0) * HD_;
    const int laneoff = (2 * l31 + hi) * 8;
    const bf16_t* kl = kt + (size_t)bh * (S_ * 64) + (size_t)thalf * 65536 + laneoff;
    const bf16_t* vl = vt + (size_t)bh * (S_ * 64) + (size_t)thalf * 65536 + laneoff;

    bf16x8 qf[4];
    const bf16_t* qptr = Qp + l31 * HD_ + 8 * hi;
#pragma unroll
    for (int j = 0; j < 4; ++j) qf[j] = ldb8(qptr + 16 * j);

    f32x16 o0 = {0.f, 0.f, 0.f, 0.f, 0.f, 0.f, 0.f, 0.f,
                 0.f, 0.f, 0.f, 0.f, 0.f, 0.f, 0.f, 0.f};
    f32x16 o1 = o0;
    float m = -1e30f, lsum = 0.f;

    bf16x8 kE[4], kO[4];
    loadK(kl, kE);

    for (int i = 0; i < 16; ++i) {
        // even tile (kE ready)
        {
            f32x16 s = qk4(kE, qf);
            loadK(kl + 2048, kO);  // prefetch odd-tile K during softmax
            bf16x8 vv[4];
            loadV(vl, vv);         // issued early; consumed after softmax
            bf16x8 pa0, pa1;
            softmax_pa(s, m, lsum, o0, o1, hi, pa0, pa1);
            pv4(pa0, pa1, vv, o0, o1);
        }
        // odd tile (kO ready)
        {
            f32x16 s = qk4(kO, qf);
            loadK(kl + 4096, kE);  // prefetch next even-tile K (last iter: dead read)
            bf16x8 vv[4];
            loadV(vl + 2048, vv);
            bf16x8 pa0, pa1;
            softmax_pa(s, m, lsum, o0, o1, hi, pa0, pa1);
            pv4(pa0, pa1, vv, o0, o1);
        }
        kl += 4096;
        vl += 4096;
    }

    // ---- merge t-halves: waves (p, p+2) share q-rows ----
    float lfull = lsum + __shfl_xor(lsum, 32);  // full row sum for q = l31
    if (thalf) {
        if (!hi) {
            lm[pair][l31] = m;
            ll[pair][l31] = lfull;
        }
#pragma unroll
        for (int r = 0; r < 16; ++r) {
            lo[pair][0][r][lane] = o0[r];
            lo[pair][1][r][lane] = o1[r];
        }
    }
    __syncthreads();
    if (!thalf) {
        float mb_ = lm[pair][l31];
        float lb_ = ll[pair][l31];
        float ms = fmaxf(m, mb_);
        float ca = __builtin_amdgcn_exp2f(m - ms);
        float cb = __builtin_amdgcn_exp2f(mb_ - ms);
        float invL = 1.0f / (lfull * ca + lb_ * cb);
        const int b = bh >> 4, h = bh & 15;
        bf16_t* op = attn + ((size_t)b * S_ + q0) * D_ + h * HD_;
#pragma unroll
        for (int r = 0; r < 16; ++r) {
            int q = (r & 3) + 8 * (r >> 2) + 4 * hi;
            float caq = __shfl(ca, q);
            float cbq = __shfl(cb, q);
            float invq = __shfl(invL, q);
            float O0 = (o0[r] * caq + lo[pair][0][r][lane] * cbq) * invq;
            float O1 = (o1[r] * caq + lo[pair][1][r][lane] * cbq) * invq;
            op[(size_t)q * D_ + l31] = (bf16_t)O0;
            op[(size_t)q * D_ + 32 + l31] = (bf16_t)O1;
        }
    }
}

// ---------------- GEMM2: out = attn @ w_o^T + b_o (fp32 out) ----------------
__global__ __launch_bounds__(256) void k_gemm_out(const bf16_t* __restrict__ attn,
                                                  const bf16_t* __restrict__ wob,
                                                  const float* __restrict__ bo,
                                                  float* __restrict__ out) {
    __shared__ bf16_t ldsA[128 * 32];
    __shared__ bf16_t ldsB[128 * 32];
    f32x4 acc[4][4];
    gemm_core(attn, wob, 1024, ldsA, ldsB, acc, blockIdx.x * 128, blockIdx.y * 128);

    const int tid = threadIdx.x;
    const int wave = tid >> 6, lane = tid & 63;
    const int g = lane >> 4, q16 = lane & 15;
    const int wm = wave >> 1, wn = wave & 1;
    const int mb = blockIdx.x * 128, nb = blockIdx.y * 128;
#pragma unroll
    for (int j = 0; j < 4; ++j) {
        int n = nb + wn * 64 + j * 16 + q16;
        float bias = bo[n];
#pragma unroll
        for (int i = 0; i < 4; ++i) {
            int m0 = mb + wm * 64 + i * 16 + 4 * g;
#pragma unroll
            for (int r = 0; r < 4; ++r)
                out[(size_t)(m0 + r) * D_ + n] = acc[i][j][r] + bias;
        }
    }
}

extern "C" void kernel_launch(void* const* d_in, const int* in_sizes, int n_in,
                              void* d_out, int out_size, void* d_ws, size_t ws_size,
                              hipStream_t stream) {
    const float* x    = (const float*)d_in[0];
    const float* rot  = (const float*)d_in[1];
    const float* wqkv = (const float*)d_in[2];
    const float* bqkv = (const float*)d_in[3];
    const float* wo   = (const float*)d_in[4];
    const float* bo   = (const float*)d_in[5];
    float* out = (float*)d_out;

    char* ws = (char*)d_ws;
    bf16_t* xb   = (bf16_t*)(ws);                        // 8 MB  [4096,1024]
    bf16_t* wqb  = (bf16_t*)(ws + ((size_t)8 << 20));    // 6 MB  [3072,1024]
    bf16_t* wob  = (bf16_t*)(ws + ((size_t)14 << 20));   // 2 MB  [1024,1024]
    bf16_t* qa   = (bf16_t*)(ws + ((size_t)16 << 20));   // 8 MB  [B,H,S,64]
    bf16_t* kt   = (bf16_t*)(ws + ((size_t)24 << 20));   // 8 MB  K tiled
    bf16_t* vt   = (bf16_t*)(ws + ((size_t)32 << 20));   // 8 MB  V tiled
    bf16_t* attn = (bf16_t*)(ws + ((size_t)40 << 20));   // 8 MB  [4096,1024]

    k_cvt3<<<2048, 256, 0, stream>>>(x, wqkv, wo, xb, wqb, wob);
    k_gemm_qkv<<<dim3(32, 24), 256, 0, stream>>>(xb, wqb, bqkv, rot, qa, kt, vt);
    k_attn<<<dim3(32, 32), 256, 0, stream>>>(qa, kt, vt, attn);
    k_gemm_out<<<dim3(32, 8), 256, 0, stream>>>(attn, wob, bo, out);
}